// Round 1
// baseline (167.107 us; speedup 1.0000x reference)
//
#include <hip/hip_runtime.h>
#include <math.h>

#define D 64
#define K 512
#define BLOCK 256
#define KSLICE 64               // K / NSLICES
#define NSLICES 8
#define NPART 32                // partial histograms: 256 blocks / 32 = 8-way contention

// Bit-level emulation of the harness's numpy fp32 reference (validated at
// absmax 0.0):
//   dist[i,k] = fp32( fp32(sx[i] + se[k]) - 2*dot[i,k] )
// sx/se = numpy pairwise sums (8-accumulator kernel, contraction OFF),
// dot = sequential single-accumulator fmaf chain over j=0..63.
// argmin strict-<, first occurrence.
//
// This round: scan's e-operand path moves from broadcast ds_read_b128 (LDS
// pipe-bound: 1 DS per 4.4 VALU vs ~16:1 balance) to wave-uniform global
// reads -> s_load through the scalar pipe. LDS drops 33KB -> 512B; slices
// 4 -> 8 for occupancy (grid 2048, ~5-6 waves/SIMD). merge's 256-way
// contended device-scope histogram atomics -> 32 partial hists + finalize
// reduce. Per-(row,k) arithmetic unchanged.

// numpy pairwise sum of v[j]*v[j], n=64; contraction OFF so each mul and
// add rounds separately, exactly like numpy's scalar kernel.
__device__ __forceinline__ float np_sumsq64(const float* v) {
#pragma clang fp contract(off)
    float r[8];
#pragma unroll
    for (int m = 0; m < 8; ++m) r[m] = v[m] * v[m];
#pragma unroll
    for (int i = 8; i < 64; i += 8) {
#pragma unroll
        for (int m = 0; m < 8; ++m) r[m] = r[m] + v[i + m] * v[i + m];
    }
    return ((r[0] + r[1]) + (r[2] + r[3])) + ((r[4] + r[5]) + (r[6] + r[7]));
}

// Pass 1: each block scans KSLICE codes for BLOCK rows; writes (d, k) into
// the q-region of d_out (stash), later overwritten by vq_merge.
__global__ __launch_bounds__(BLOCK, 4) void vq_scan(
    const float* __restrict__ x, const float* __restrict__ emb,
    float* __restrict__ stash, int N)
{
    __shared__ float se_s[KSLICE];      // 256 B — LDS no longer caps occupancy

    const int tid = threadIdx.x;
    const int kbase = blockIdx.y * KSLICE;

    // numpy-pairwise ||e_k||^2 (one wave; per-lane vector loads)
    if (tid < KSLICE) {
        float er[D];
        const float4* e4 = (const float4*)(emb + (size_t)(kbase + tid) * D);
#pragma unroll
        for (int j = 0; j < D / 4; ++j) {
            float4 v = e4[j];
            er[4 * j + 0] = v.x; er[4 * j + 1] = v.y;
            er[4 * j + 2] = v.z; er[4 * j + 3] = v.w;
        }
        se_s[tid] = np_sumsq64(er);
    }
    __syncthreads();

    const int row = blockIdx.x * BLOCK + tid;
    if (row >= N) return;

    float xr[D];
    {
        const float4* xp = (const float4*)(x + (size_t)row * D);
#pragma unroll
        for (int j = 0; j < D / 4; ++j) {
            float4 v = xp[j];
            xr[4 * j + 0] = v.x; xr[4 * j + 1] = v.y;
            xr[4 * j + 2] = v.z; xr[4 * j + 3] = v.w;
        }
    }
    const float sx = np_sumsq64(xr);

    // e loads are wave-uniform (kbase, k uniform; emb readonly+restrict)
    // -> compiler emits s_load_dwordx4/x16; FMA reads e from SGPR.
    // 4 interleaved sequential fmaf chains: ILP for FMA latency + SMEM slack.
    const float* ebase = emb + (size_t)kbase * D;
    float bestd = INFINITY;
    int bi = 0;
    for (int k = 0; k < KSLICE; k += 4) {
        float a0 = 0.f, a1 = 0.f, a2 = 0.f, a3 = 0.f;
        const float4* e0 = (const float4*)(ebase + (size_t)(k + 0) * D);
        const float4* e1 = (const float4*)(ebase + (size_t)(k + 1) * D);
        const float4* e2 = (const float4*)(ebase + (size_t)(k + 2) * D);
        const float4* e3 = (const float4*)(ebase + (size_t)(k + 3) * D);
#pragma unroll
        for (int j = 0; j < D / 4; ++j) {
            float4 ea = e0[j];              // uniform -> s_load
            float4 eb = e1[j];
            float4 ec = e2[j];
            float4 ed = e3[j];
            a0 = fmaf(xr[4 * j + 0], ea.x, a0);
            a1 = fmaf(xr[4 * j + 0], eb.x, a1);
            a2 = fmaf(xr[4 * j + 0], ec.x, a2);
            a3 = fmaf(xr[4 * j + 0], ed.x, a3);
            a0 = fmaf(xr[4 * j + 1], ea.y, a0);
            a1 = fmaf(xr[4 * j + 1], eb.y, a1);
            a2 = fmaf(xr[4 * j + 1], ec.y, a2);
            a3 = fmaf(xr[4 * j + 1], ed.y, a3);
            a0 = fmaf(xr[4 * j + 2], ea.z, a0);
            a1 = fmaf(xr[4 * j + 2], eb.z, a1);
            a2 = fmaf(xr[4 * j + 2], ec.z, a2);
            a3 = fmaf(xr[4 * j + 2], ed.z, a3);
            a0 = fmaf(xr[4 * j + 3], ea.w, a0);
            a1 = fmaf(xr[4 * j + 3], eb.w, a1);
            a2 = fmaf(xr[4 * j + 3], ec.w, a2);
            a3 = fmaf(xr[4 * j + 3], ed.w, a3);
        }
        const float4 se4 = *(const float4*)&se_s[k];
        float d0 = (sx + se4.x) - 2.0f * a0;    // same rounding as ref
        float d1 = (sx + se4.y) - 2.0f * a1;
        float d2 = (sx + se4.z) - 2.0f * a2;
        float d3 = (sx + se4.w) - 2.0f * a3;
        if (d0 < bestd) { bestd = d0; bi = k; }      // k ascending: first-min
        if (d1 < bestd) { bestd = d1; bi = k + 1; }
        if (d2 < bestd) { bestd = d2; bi = k + 2; }
        if (d3 < bestd) { bestd = d3; bi = k + 3; }
    }

    // stash (d, global_k) as float2 at q_out[row*64 + 2*slice] (8B-aligned)
    float2 p; p.x = bestd; p.y = (float)(kbase + bi);
    *(float2*)(stash + (size_t)row * D + 2 * blockIdx.y) = p;
}

// Pass 2: merge 8 slice partials (slice order = k order -> first occurrence),
// gather winning code, write q/idx, loss partials, partial histograms.
__global__ __launch_bounds__(BLOCK) void vq_merge(
    const float* __restrict__ x, const float* __restrict__ emb,
    float* __restrict__ q_out, float* __restrict__ idx_out,
    float* __restrict__ block_sums, int* __restrict__ part_hist, int N)
{
    __shared__ int hist[K];
    __shared__ float red[BLOCK / 64];
    const int tid = threadIdx.x;
    for (int k = tid; k < K; k += BLOCK) hist[k] = 0;
    __syncthreads();

    const int row = blockIdx.x * BLOCK + tid;
    float s = 0.f;
    if (row < N) {
        float bestd = INFINITY;
        int bi = 0;
#pragma unroll
        for (int sl = 0; sl < NSLICES; ++sl) {
            float2 p = *(const float2*)(q_out + (size_t)row * D + 2 * sl);
            if (p.x < bestd) { bestd = p.x; bi = (int)p.y; }
        }
        atomicAdd(&hist[bi], 1);

        const float4* xp = (const float4*)(x + (size_t)row * D);
        const float4* ep = (const float4*)(emb + (size_t)bi * D);
        float4* qp = (float4*)(q_out + (size_t)row * D);
#pragma unroll
        for (int j = 0; j < D / 4; ++j) {
            float4 xv = xp[j];
            float4 e  = ep[j];
            float dx0 = e.x - xv.x, dx1 = e.y - xv.y;
            float dx2 = e.z - xv.z, dx3 = e.w - xv.w;
            s = fmaf(dx0, dx0, s);
            s = fmaf(dx1, dx1, s);
            s = fmaf(dx2, dx2, s);
            s = fmaf(dx3, dx3, s);
            float4 qs;  // straight-through: x + (q - x)
            qs.x = xv.x + dx0; qs.y = xv.y + dx1;
            qs.z = xv.z + dx2; qs.w = xv.w + dx3;
            qp[j] = qs;
        }
        idx_out[row] = (float)bi;
    }

    for (int off = 32; off; off >>= 1) s += __shfl_down(s, off, 64);
    if ((tid & 63) == 0) red[tid >> 6] = s;
    __syncthreads();            // also orders hist atomics before readout
    if (tid == 0) {
        float t = 0.f;
#pragma unroll
        for (int w = 0; w < BLOCK / 64; ++w) t += red[w];
        block_sums[blockIdx.x] = t;
    }
    // per-block hist -> one of 32 partial hists (8-way contention, skip zeros)
    const int part = (int)(blockIdx.x & (NPART - 1));
    for (int k = tid; k < K; k += BLOCK) {
        int h = hist[k];
        if (h) atomicAdd(&part_hist[part * K + k], h);
    }
}

__global__ __launch_bounds__(512) void vq_finalize(
    const float* __restrict__ block_sums, int nblocks,
    const int* __restrict__ part_hist, float* __restrict__ out_loss,
    float* __restrict__ out_perp, float inv_nelem, float inv_rows)
{
    const int tid = threadIdx.x;
    double ls = 0.0;
    for (int i = tid; i < nblocks; i += 512) ls += (double)block_sums[i];
    int c = 0;
#pragma unroll
    for (int pp = 0; pp < NPART; ++pp) c += part_hist[pp * K + tid];  // coalesced
    double ps = 0.0;
    {
        float p = (float)c * inv_rows;          // tid < 512 == K
        ps = (double)(p * logf(p + 1e-10f));
    }
    for (int off = 32; off; off >>= 1) {
        ls += __shfl_down(ls, off, 64);
        ps += __shfl_down(ps, off, 64);
    }
    __shared__ double l8[8], p8[8];
    if ((tid & 63) == 0) { l8[tid >> 6] = ls; p8[tid >> 6] = ps; }
    __syncthreads();
    if (tid == 0) {
        double L = 0.0, P = 0.0;
#pragma unroll
        for (int w = 0; w < 8; ++w) { L += l8[w]; P += p8[w]; }
        // loss = q_latent + 0.25*e_latent; forward values identical
        *out_loss = 1.25f * (float)(L * (double)inv_nelem);
        *out_perp = expf((float)(-P));
    }
}

extern "C" void kernel_launch(void* const* d_in, const int* in_sizes, int n_in,
                              void* d_out, int out_size, void* d_ws, size_t ws_size,
                              hipStream_t stream) {
    const float* x   = (const float*)d_in[0];
    const float* emb = (const float*)d_in[1];
    const int N = in_sizes[0] / D;          // 65536 rows
    const int nblocks = (N + BLOCK - 1) / BLOCK;

    float* out      = (float*)d_out;
    float* loss_out = out;                  // [0]
    float* q_out    = out + 1;              // [1 .. N*D]
    float* perp_out = out + 1 + (size_t)N * D;
    float* idx_out  = perp_out + 1;         // [.. + N]

    float* block_sums = (float*)d_ws;
    int*   part_hist  = (int*)((char*)d_ws + (((size_t)nblocks * 4 + 255) & ~(size_t)255));

    hipMemsetAsync(part_hist, 0, NPART * K * sizeof(int), stream);
    dim3 sgrid(nblocks, NSLICES);
    vq_scan<<<sgrid, BLOCK, 0, stream>>>(x, emb, q_out, N);
    vq_merge<<<nblocks, BLOCK, 0, stream>>>(x, emb, q_out, idx_out,
                                            block_sums, part_hist, N);
    vq_finalize<<<1, 512, 0, stream>>>(block_sums, nblocks, part_hist,
                                       loss_out, perp_out,
                                       1.0f / (float)((size_t)N * D),
                                       1.0f / (float)N);
}

// Round 2
// 139.783 us; speedup vs baseline: 1.1955x; 1.1955x over previous
//
#include <hip/hip_runtime.h>
#include <math.h>

#define D 64
#define K 512
#define BLOCK 256
#define ROWS 128            // rows per block
#define KT 128              // codes per staged e-tile
#define NKT (K / KT)        // 4
#define NPART 32

// Bit-level emulation of the harness's numpy fp32 reference (validated at
// absmax 0.0):
//   dist[i,k] = fp32( fp32(sx[i] + se[k]) - 2*dot[i,k] )
// sx/se = numpy pairwise sums (8-accumulator kernel, contraction OFF),
// dot = sequential single-accumulator fmaf chain over j=0..63 (ascending).
// argmin strict-<, first occurrence.
//
// Round-2 bottleneck was FMA:load = 4:1 (1 row/thread). This version is a
// GEMM-style register tile: 8 rows x 8 codes per thread, both operands in
// XOR-swizzled LDS -> 256 FMAs per 16 ds_read_b128 (16:1). Block = 128 rows
// x all 512 codes (4 e-tiles), so argmin/gather/loss/hist fuse in (no stash,
// no merge pass). Per-(row,k) arithmetic chains unchanged.

__device__ __forceinline__ float np_sumsq64(const float* v) {
#pragma clang fp contract(off)
    float r[8];
#pragma unroll
    for (int m = 0; m < 8; ++m) r[m] = v[m] * v[m];
#pragma unroll
    for (int i = 8; i < 64; i += 8) {
#pragma unroll
        for (int m = 0; m < 8; ++m) r[m] = r[m] + v[i + m] * v[i + m];
    }
    return ((r[0] + r[1]) + (r[2] + r[3])) + ((r[4] + r[5]) + (r[6] + r[7]));
}

__global__ __launch_bounds__(BLOCK, 2) void vq_fused(
    const float* __restrict__ x, const float* __restrict__ emb,
    float* __restrict__ q_out, float* __restrict__ idx_out,
    float* __restrict__ block_sums, int* __restrict__ part_hist, int N)
{
    // swizzled tiles: float4 index = row*16 + (jc ^ ((row>>3)&7))
    __shared__ float4 xs4[ROWS * 16];   // 32 KB
    __shared__ float4 es4[KT * 16];     // 32 KB (reused as bests[] after k-loop)
    __shared__ float sx_s[ROWS];
    __shared__ float se_s[KT];
    __shared__ int hist[K];
    __shared__ float red[BLOCK / 64];

    const int tid = threadIdx.x;
    const int rg = tid & 15;            // row-group: rows rg*8..rg*8+7
    const int cg = tid >> 4;            // code-group: codes cg*8..cg*8+7
    const int rowbase = blockIdx.x * ROWS;

    for (int k2 = tid; k2 < K; k2 += BLOCK) hist[k2] = 0;

    // ---- stage x tile (coalesced global, swizzled LDS) ----
    const float4* xsrc = (const float4*)(x + (size_t)rowbase * D);
#pragma unroll
    for (int i = 0; i < (ROWS * 16) / BLOCK; ++i) {      // 8 float4/thread
        int f = tid + i * BLOCK;
        int row = f >> 4, jc = f & 15;
        xs4[row * 16 + (jc ^ ((row >> 3) & 7))] = xsrc[f];
    }
    __syncthreads();

    // ---- sx prologue: numpy-pairwise ||x_row||^2 from LDS copies ----
    if (tid < ROWS) {
        float xr[D];
        const int sw = (tid >> 3) & 7;
#pragma unroll
        for (int jc = 0; jc < 16; ++jc) {
            float4 v = xs4[tid * 16 + (jc ^ sw)];
            xr[4 * jc + 0] = v.x; xr[4 * jc + 1] = v.y;
            xr[4 * jc + 2] = v.z; xr[4 * jc + 3] = v.w;
        }
        sx_s[tid] = np_sumsq64(xr);
    }
    // visible to readers after the tile-0 staging barrier below

    float bd[8], bkf[8];
#pragma unroll
    for (int r = 0; r < 8; ++r) { bd[r] = INFINITY; bkf[r] = 0.f; }

    const int xbase = rg * 8, ebase = cg * 8;
    const int swx0 = rg & 7, swe0 = cg & 7;

    for (int kt = 0; kt < NKT; ++kt) {
        // ---- stage e tile ----
        const float4* esrc = (const float4*)(emb + (size_t)kt * KT * D);
#pragma unroll
        for (int i = 0; i < (KT * 16) / BLOCK; ++i) {
            int f = tid + i * BLOCK;
            int row = f >> 4, jc = f & 15;
            es4[row * 16 + (jc ^ ((row >> 3) & 7))] = esrc[f];
        }
        __syncthreads();

        // numpy-pairwise ||e_k||^2 (read after barrier; se_s consumed only
        // after the post-jc barrier below)
        if (tid < KT) {
            float er[D];
            const int sw = (tid >> 3) & 7;
#pragma unroll
            for (int jc = 0; jc < 16; ++jc) {
                float4 v = es4[tid * 16 + (jc ^ sw)];
                er[4 * jc + 0] = v.x; er[4 * jc + 1] = v.y;
                er[4 * jc + 2] = v.z; er[4 * jc + 3] = v.w;
            }
            se_s[tid] = np_sumsq64(er);
        }

        float acc[8][8];
#pragma unroll
        for (int r = 0; r < 8; ++r)
#pragma unroll
            for (int c = 0; c < 8; ++c) acc[r][c] = 0.f;

        // 16:1 FMA:DS inner loop; each acc is a sequential ascending-j chain
#pragma unroll 2
        for (int jc = 0; jc < 16; ++jc) {
            float4 xa[8], eb[8];
#pragma unroll
            for (int r = 0; r < 8; ++r)
                xa[r] = xs4[(xbase + r) * 16 + (jc ^ swx0)];
#pragma unroll
            for (int c = 0; c < 8; ++c)
                eb[c] = es4[(ebase + c) * 16 + (jc ^ swe0)];
#pragma unroll
            for (int r = 0; r < 8; ++r)
#pragma unroll
                for (int c = 0; c < 8; ++c) {
                    acc[r][c] = fmaf(xa[r].x, eb[c].x, acc[r][c]);
                    acc[r][c] = fmaf(xa[r].y, eb[c].y, acc[r][c]);
                    acc[r][c] = fmaf(xa[r].z, eb[c].z, acc[r][c]);
                    acc[r][c] = fmaf(xa[r].w, eb[c].w, acc[r][c]);
                }
        }
        __syncthreads();    // all e_s reads done; se_s writes visible

        // dist + running first-min (codes ascending within thread & tiles)
        const int kglob = kt * KT + ebase;
        float sev[8];
#pragma unroll
        for (int c = 0; c < 8; ++c) sev[c] = se_s[ebase + c];
#pragma unroll
        for (int r = 0; r < 8; ++r) {
            float sxv = sx_s[xbase + r];
#pragma unroll
            for (int c = 0; c < 8; ++c) {
                float dcur = (sxv + sev[c]) - 2.0f * acc[r][c];  // ref rounding
                if (dcur < bd[r]) { bd[r] = dcur; bkf[r] = (float)(kglob + c); }
            }
        }
        // next staging overwrites es4 only after its own barrier-free window:
        // all es4 reads ended before the barrier above; se_s of this tile is
        // only read pre-next-barrier. Safe.
    }

    __syncthreads();
    // cross-thread argmin: lexicographic (d, k) over the 16 code-groups
    float2* bests = (float2*)es4;       // 16 KB alias, e-tiles dead now
#pragma unroll
    for (int r = 0; r < 8; ++r)
        bests[(xbase + r) * 16 + cg] = make_float2(bd[r], bkf[r]);
    __syncthreads();

    float s = 0.f;
    if (tid < ROWS) {
        float bdd = INFINITY, bjf = 1e30f;
#pragma unroll
        for (int g = 0; g < 16; ++g) {
            float2 p = bests[tid * 16 + g];
            if (p.x < bdd || (p.x == bdd && p.y < bjf)) { bdd = p.x; bjf = p.y; }
        }
        const int bi = (int)bjf;
        atomicAdd(&hist[bi], 1);

        const int rowg = rowbase + tid;
        const float4* ep = (const float4*)(emb + (size_t)bi * D);
        float4* qp = (float4*)(q_out + (size_t)rowg * D);
        const int sw = (tid >> 3) & 7;
#pragma unroll
        for (int jc = 0; jc < 16; ++jc) {
            float4 xv = xs4[tid * 16 + (jc ^ sw)];   // bit-identical x
            float4 e  = ep[jc];
            float dx0 = e.x - xv.x, dx1 = e.y - xv.y;
            float dx2 = e.z - xv.z, dx3 = e.w - xv.w;
            s = fmaf(dx0, dx0, s);
            s = fmaf(dx1, dx1, s);
            s = fmaf(dx2, dx2, s);
            s = fmaf(dx3, dx3, s);
            float4 qs;  // straight-through: x + (q - x)
            qs.x = xv.x + dx0; qs.y = xv.y + dx1;
            qs.z = xv.z + dx2; qs.w = xv.w + dx3;
            qp[jc] = qs;
        }
        idx_out[rowg] = (float)bi;
    }

    // loss partial (inactive waves contribute 0)
    for (int off = 32; off; off >>= 1) s += __shfl_down(s, off, 64);
    if ((tid & 63) == 0) red[tid >> 6] = s;
    __syncthreads();    // also orders hist atomics before flush
    if (tid == 0) {
        float t = 0.f;
#pragma unroll
        for (int w = 0; w < BLOCK / 64; ++w) t += red[w];
        block_sums[blockIdx.x] = t;
    }
    const int part = (int)(blockIdx.x & (NPART - 1));
    for (int k2 = tid; k2 < K; k2 += BLOCK) {
        int h = hist[k2];
        if (h) atomicAdd(&part_hist[part * K + k2], h);
    }
}

__global__ __launch_bounds__(512) void vq_finalize(
    const float* __restrict__ block_sums, int nblocks,
    const int* __restrict__ part_hist, float* __restrict__ out_loss,
    float* __restrict__ out_perp, float inv_nelem, float inv_rows)
{
    const int tid = threadIdx.x;
    double ls = 0.0;
    for (int i = tid; i < nblocks; i += 512) ls += (double)block_sums[i];
    int c = 0;
#pragma unroll
    for (int pp = 0; pp < NPART; ++pp) c += part_hist[pp * K + tid];  // coalesced
    double ps = 0.0;
    {
        float p = (float)c * inv_rows;          // tid < 512 == K
        ps = (double)(p * logf(p + 1e-10f));
    }
    for (int off = 32; off; off >>= 1) {
        ls += __shfl_down(ls, off, 64);
        ps += __shfl_down(ps, off, 64);
    }
    __shared__ double l8[8], p8[8];
    if ((tid & 63) == 0) { l8[tid >> 6] = ls; p8[tid >> 6] = ps; }
    __syncthreads();
    if (tid == 0) {
        double L = 0.0, P = 0.0;
#pragma unroll
        for (int w = 0; w < 8; ++w) { L += l8[w]; P += p8[w]; }
        // loss = q_latent + 0.25*e_latent; forward values identical
        *out_loss = 1.25f * (float)(L * (double)inv_nelem);
        *out_perp = expf((float)(-P));
    }
}

extern "C" void kernel_launch(void* const* d_in, const int* in_sizes, int n_in,
                              void* d_out, int out_size, void* d_ws, size_t ws_size,
                              hipStream_t stream) {
    const float* x   = (const float*)d_in[0];
    const float* emb = (const float*)d_in[1];
    const int N = in_sizes[0] / D;          // 65536 rows
    const int nblocks = N / ROWS;           // 512

    float* out      = (float*)d_out;
    float* loss_out = out;                  // [0]
    float* q_out    = out + 1;              // [1 .. N*D]
    float* perp_out = out + 1 + (size_t)N * D;
    float* idx_out  = perp_out + 1;         // [.. + N]

    float* block_sums = (float*)d_ws;
    int*   part_hist  = (int*)((char*)d_ws + (((size_t)nblocks * 4 + 255) & ~(size_t)255));

    hipMemsetAsync(part_hist, 0, NPART * K * sizeof(int), stream);
    vq_fused<<<nblocks, BLOCK, 0, stream>>>(x, emb, q_out, idx_out,
                                            block_sums, part_hist, N);
    vq_finalize<<<1, 512, 0, stream>>>(block_sums, nblocks, part_hist,
                                       loss_out, perp_out,
                                       1.0f / (float)((size_t)N * D),
                                       1.0f / (float)N);
}